// Round 1
// baseline (258.953 us; speedup 1.0000x reference)
//
#include <hip/hip_runtime.h>

#define NBINS 15

// One 16-lane group per row (C=64 floats = 16 x float4).
// gbins layout: [0..14]=count, [15..29]=conf_sum, [30..44]=acc_sum
__global__ __launch_bounds__(256) void ece_partial(
    const float* __restrict__ logits,
    const int*   __restrict__ labels,
    const float* __restrict__ temperature,
    float*       __restrict__ gbins,
    int N)
{
    __shared__ float sbins[3 * NBINS];
    const int tid = threadIdx.x;
    if (tid < 3 * NBINS) sbins[tid] = 0.0f;
    __syncthreads();

    const float invT = 1.0f / temperature[0];

    const int lane        = tid & 63;
    const int waveInBlock = tid >> 6;
    const int wavesPerBlk = blockDim.x >> 6;
    const long long gWave      = (long long)blockIdx.x * wavesPerBlk + waveInBlock;
    const long long totalWaves = (long long)gridDim.x * wavesPerBlk;

    const int sub       = lane & 15;  // float4 index within the row
    const int rowInWave = lane >> 4;  // 0..3: each wave covers 4 rows

    const float4* __restrict__ logits4 = reinterpret_cast<const float4*>(logits);

    for (long long r0 = gWave * 4; r0 < (long long)N; r0 += totalWaves * 4) {
        const long long row = r0 + rowInWave;
        const bool valid = row < (long long)N;

        float4 v;
        if (valid) v = logits4[row * 16 + sub];
        else       v = make_float4(-1e30f, -1e30f, -1e30f, -1e30f);

        // local max + argmax (class index = sub*4 + j), first-occurrence ties
        float m  = v.x; int am = sub * 4;
        if (v.y > m) { m = v.y; am = sub * 4 + 1; }
        if (v.z > m) { m = v.z; am = sub * 4 + 2; }
        if (v.w > m) { m = v.w; am = sub * 4 + 3; }

        #pragma unroll
        for (int d = 1; d < 16; d <<= 1) {
            float om = __shfl_xor(m, d);
            int   oa = __shfl_xor(am, d);
            if (om > m || (om == m && oa < am)) { m = om; am = oa; }
        }

        // sum of exp((x - max)/T); conf = 1/sum
        float s = __expf((v.x - m) * invT) + __expf((v.y - m) * invT)
                + __expf((v.z - m) * invT) + __expf((v.w - m) * invT);
        #pragma unroll
        for (int d = 1; d < 16; d <<= 1) s += __shfl_xor(s, d);

        if (valid && sub == 0) {
            const float conf = 1.0f / s;
            const int   lbl  = labels[row];
            const float acc  = (am == lbl) ? 1.0f : 0.0f;
            int bin = (int)ceilf(conf * (float)NBINS) - 1;
            bin = bin < 0 ? 0 : (bin > NBINS - 1 ? NBINS - 1 : bin);
            atomicAdd(&sbins[bin],             1.0f);
            atomicAdd(&sbins[NBINS + bin],     conf);
            atomicAdd(&sbins[2 * NBINS + bin], acc);
        }
    }

    __syncthreads();
    if (tid < 3 * NBINS) {
        const float v = sbins[tid];
        if (v != 0.0f) atomicAdd(&gbins[tid], v);
    }
}

__global__ void ece_finalize(const float* __restrict__ gbins,
                             float* __restrict__ out, float invN)
{
    if (threadIdx.x == 0 && blockIdx.x == 0) {
        float ece = 0.0f, mce = 0.0f;
        #pragma unroll
        for (int i = 0; i < NBINS; ++i) {
            const float c  = gbins[i];
            const float cs = gbins[NBINS + i];
            const float as = gbins[2 * NBINS + i];
            if (c > 0.0f) {
                const float gap = fabsf(cs / c - as / c);
                ece += gap * (c * invN);
                mce = fmaxf(mce, gap);
            }
        }
        out[0] = ece;
        out[1] = mce;
    }
}

extern "C" void kernel_launch(void* const* d_in, const int* in_sizes, int n_in,
                              void* d_out, int out_size, void* d_ws, size_t ws_size,
                              hipStream_t stream) {
    const float* logits      = (const float*)d_in[0];
    const int*   labels      = (const int*)d_in[1];
    const float* temperature = (const float*)d_in[2];
    float*       out         = (float*)d_out;
    float*       gbins       = (float*)d_ws;

    const int N = in_sizes[1];  // number of rows / labels

    hipMemsetAsync(gbins, 0, 3 * NBINS * sizeof(float), stream);

    const int block = 256;
    const int grid  = 2048;
    ece_partial<<<grid, block, 0, stream>>>(logits, labels, temperature, gbins, N);
    ece_finalize<<<1, 64, 0, stream>>>(gbins, out, 1.0f / (float)N);
}

// Round 2
// 189.563 us; speedup vs baseline: 1.3661x; 1.3661x over previous
//
#include <hip/hip_runtime.h>

#define NBINS 15

typedef float f32x4 __attribute__((ext_vector_type(4)));

// 4 lanes per row, 16 rows per wave-iteration.
// Lane layout: sub = lane&3 (float4 slot), rIw = lane>>2 (row within wave).
// Lane loads float4 indices {sub, sub+4, sub+8, sub+12} of its row, so each
// 4-lane group covers a contiguous 64B chunk per load instruction.
// gbins layout: [0..14]=count, [15..29]=conf_sum, [30..44]=acc_sum
__global__ __launch_bounds__(256) void ece_partial(
    const f32x4* __restrict__ logits4,
    const int*   __restrict__ labels,
    const float* __restrict__ temperature,
    float*       __restrict__ gbins,
    int N)
{
    __shared__ float sbins[3 * NBINS];
    const int tid = threadIdx.x;
    if (tid < 3 * NBINS) sbins[tid] = 0.0f;
    __syncthreads();

    const float invT = 1.0f / temperature[0];

    const int lane = tid & 63;
    const int wIn  = tid >> 6;
    const long long gWave = (long long)blockIdx.x * 4 + wIn;
    const long long nWave = (long long)gridDim.x * 4;

    const int sub = lane & 3;   // float4 slot group
    const int rIw = lane >> 2;  // row within wave (0..15)

    for (long long r0 = gWave * 16; r0 < (long long)N; r0 += nWave * 16) {
        const long long row = r0 + rIw;
        const bool valid = row < (long long)N;
        const long long rc = valid ? row : (long long)(N - 1);

        // 4 independent 16B loads, issued before any dependent work.
        const f32x4* p = logits4 + rc * 16 + sub;
        const f32x4 v0 = __builtin_nontemporal_load(p);      // cols 4*sub   +0..3
        const f32x4 v1 = __builtin_nontemporal_load(p + 4);  // cols 4*sub+16+0..3
        const f32x4 v2 = __builtin_nontemporal_load(p + 8);  // cols 4*sub+32+0..3
        const f32x4 v3 = __builtin_nontemporal_load(p + 12); // cols 4*sub+48+0..3

        // local max + argmax over 16 values, first-occurrence ties
        // (within-lane column order is strictly increasing: 4sub+16k+j)
        float m  = v0.x;
        int   am = 4 * sub;
        {
            const int b = 4 * sub;
            if (v0.y > m) { m = v0.y; am = b + 1; }
            if (v0.z > m) { m = v0.z; am = b + 2; }
            if (v0.w > m) { m = v0.w; am = b + 3; }
            if (v1.x > m) { m = v1.x; am = b + 16; }
            if (v1.y > m) { m = v1.y; am = b + 17; }
            if (v1.z > m) { m = v1.z; am = b + 18; }
            if (v1.w > m) { m = v1.w; am = b + 19; }
            if (v2.x > m) { m = v2.x; am = b + 32; }
            if (v2.y > m) { m = v2.y; am = b + 33; }
            if (v2.z > m) { m = v2.z; am = b + 34; }
            if (v2.w > m) { m = v2.w; am = b + 35; }
            if (v3.x > m) { m = v3.x; am = b + 48; }
            if (v3.y > m) { m = v3.y; am = b + 49; }
            if (v3.z > m) { m = v3.z; am = b + 50; }
            if (v3.w > m) { m = v3.w; am = b + 51; }
        }

        // 2-step butterfly over the 4-lane group (smaller index wins ties)
        #pragma unroll
        for (int d = 1; d < 4; d <<= 1) {
            const float om = __shfl_xor(m, d);
            const int   oa = __shfl_xor(am, d);
            if (om > m || (om == m && oa < am)) { m = om; am = oa; }
        }

        // sum of exp((x - max)/T) over this lane's 16 values
        float s = __expf((v0.x - m) * invT) + __expf((v0.y - m) * invT)
                + __expf((v0.z - m) * invT) + __expf((v0.w - m) * invT)
                + __expf((v1.x - m) * invT) + __expf((v1.y - m) * invT)
                + __expf((v1.z - m) * invT) + __expf((v1.w - m) * invT)
                + __expf((v2.x - m) * invT) + __expf((v2.y - m) * invT)
                + __expf((v2.z - m) * invT) + __expf((v2.w - m) * invT)
                + __expf((v3.x - m) * invT) + __expf((v3.y - m) * invT)
                + __expf((v3.z - m) * invT) + __expf((v3.w - m) * invT);
        #pragma unroll
        for (int d = 1; d < 4; d <<= 1) s += __shfl_xor(s, d);

        if (valid && sub == 0) {
            const float conf = 1.0f / s;
            const int   lbl  = labels[row];
            const float acc  = (am == lbl) ? 1.0f : 0.0f;
            int bin = (int)ceilf(conf * (float)NBINS) - 1;
            bin = bin < 0 ? 0 : (bin > NBINS - 1 ? NBINS - 1 : bin);
            atomicAdd(&sbins[bin],             1.0f);
            atomicAdd(&sbins[NBINS + bin],     conf);
            atomicAdd(&sbins[2 * NBINS + bin], acc);
        }
    }

    __syncthreads();
    if (tid < 3 * NBINS) {
        const float v = sbins[tid];
        if (v != 0.0f) atomicAdd(&gbins[tid], v);
    }
}

__global__ void ece_finalize(const float* __restrict__ gbins,
                             float* __restrict__ out, float invN)
{
    if (threadIdx.x == 0 && blockIdx.x == 0) {
        float ece = 0.0f, mce = 0.0f;
        #pragma unroll
        for (int i = 0; i < NBINS; ++i) {
            const float c  = gbins[i];
            const float cs = gbins[NBINS + i];
            const float as = gbins[2 * NBINS + i];
            if (c > 0.0f) {
                const float gap = fabsf(cs / c - as / c);
                ece += gap * (c * invN);
                mce = fmaxf(mce, gap);
            }
        }
        out[0] = ece;
        out[1] = mce;
    }
}

extern "C" void kernel_launch(void* const* d_in, const int* in_sizes, int n_in,
                              void* d_out, int out_size, void* d_ws, size_t ws_size,
                              hipStream_t stream) {
    const f32x4* logits4     = (const f32x4*)d_in[0];
    const int*   labels      = (const int*)d_in[1];
    const float* temperature = (const float*)d_in[2];
    float*       out         = (float*)d_out;
    float*       gbins       = (float*)d_ws;

    const int N = in_sizes[1];  // number of rows / labels

    hipMemsetAsync(gbins, 0, 3 * NBINS * sizeof(float), stream);

    const int block = 256;
    const int grid  = 2048;
    ece_partial<<<grid, block, 0, stream>>>(logits4, labels, temperature, gbins, N);
    ece_finalize<<<1, 64, 0, stream>>>(gbins, out, 1.0f / (float)N);
}